// Round 8
// baseline (66.927 us; speedup 1.0000x reference)
//
#include <hip/hip_runtime.h>

// Constrained sparsemax: p = clip(z - tau, 0, u), tau s.t. sum p = 1.
// R7 core (wave-per-row, f32 segment-Newton + f64 polish, DPP reductions,
// NT stores) extended to TWO ROWS PER WAVE with instruction-interleaved
// iterations: both rows' classify blocks run back-to-back and their DPP
// reduction chains are interleaved per level, so each chain's dependent
// latency hides under the other chains' issue slots.

typedef float vfloat4 __attribute__((ext_vector_type(4)));

template<int CTRL>
__device__ __forceinline__ float dpp_zero(float v) {   // invalid lanes -> 0
  return __builtin_bit_cast(float,
    __builtin_amdgcn_update_dpp(0, __builtin_bit_cast(int, v), CTRL, 0xf, 0xf, true));
}
template<int CTRL>
__device__ __forceinline__ float dpp_ident(float v, float ident) { // invalid -> ident
  return __builtin_bit_cast(float,
    __builtin_amdgcn_update_dpp(__builtin_bit_cast(int, ident),
                                __builtin_bit_cast(int, v), CTRL, 0xf, 0xf, false));
}
__device__ __forceinline__ float rl63(float v) {
  return __builtin_bit_cast(float,
    __builtin_amdgcn_readlane(__builtin_bit_cast(int, v), 63));
}

// Four interleaved full-wave sums (each result uniform across the wave).
__device__ __forceinline__ void wave_sum4(float& a, float& b, float& c, float& d) {
#define SUM4_STEP(CT) \
  a += dpp_zero<CT>(a); b += dpp_zero<CT>(b); c += dpp_zero<CT>(c); d += dpp_zero<CT>(d);
  SUM4_STEP(0x111) SUM4_STEP(0x112) SUM4_STEP(0x114)
  SUM4_STEP(0x118) SUM4_STEP(0x142) SUM4_STEP(0x143)
#undef SUM4_STEP
  a = rl63(a); b = rl63(b); c = rl63(c); d = rl63(d);
}
__device__ __forceinline__ void wave_sum2(float& a, float& b) {
#define SUM2_STEP(CT) a += dpp_zero<CT>(a); b += dpp_zero<CT>(b);
  SUM2_STEP(0x111) SUM2_STEP(0x112) SUM2_STEP(0x114)
  SUM2_STEP(0x118) SUM2_STEP(0x142) SUM2_STEP(0x143)
#undef SUM2_STEP
  a = rl63(a); b = rl63(b);
}
// Four interleaved full-wave maxes.
__device__ __forceinline__ void wave_max4(float& a, float& b, float& c, float& d) {
  const float NI = -3.4028235e38f;
#define MAX4_STEP(CT) \
  a = fmaxf(a, dpp_ident<CT>(a, NI)); b = fmaxf(b, dpp_ident<CT>(b, NI)); \
  c = fmaxf(c, dpp_ident<CT>(c, NI)); d = fmaxf(d, dpp_ident<CT>(d, NI));
  MAX4_STEP(0x111) MAX4_STEP(0x112) MAX4_STEP(0x114)
  MAX4_STEP(0x118) MAX4_STEP(0x142) MAX4_STEP(0x143)
#undef MAX4_STEP
  a = rl63(a); b = rl63(b); c = rl63(c); d = rl63(d);
}
// Two interleaved f64 sums + two f32 sums (phase 2: S0, S1, C0, C1).
__device__ __forceinline__ void wave_sumd2_f2(double& A, double& Bv, float& c, float& d) {
#define SUMD_STEP(CT) { \
  unsigned long long xa = __builtin_bit_cast(unsigned long long, A); \
  unsigned long long xb = __builtin_bit_cast(unsigned long long, Bv); \
  int al = __builtin_amdgcn_update_dpp(0, (int)(unsigned)xa, CT, 0xf, 0xf, true); \
  int ah = __builtin_amdgcn_update_dpp(0, (int)(xa >> 32),   CT, 0xf, 0xf, true); \
  int bl = __builtin_amdgcn_update_dpp(0, (int)(unsigned)xb, CT, 0xf, 0xf, true); \
  int bh = __builtin_amdgcn_update_dpp(0, (int)(xb >> 32),   CT, 0xf, 0xf, true); \
  c += dpp_zero<CT>(c); d += dpp_zero<CT>(d); \
  A  += __builtin_bit_cast(double, ((unsigned long long)(unsigned)ah << 32) | (unsigned)al); \
  Bv += __builtin_bit_cast(double, ((unsigned long long)(unsigned)bh << 32) | (unsigned)bl); }
  SUMD_STEP(0x111) SUMD_STEP(0x112) SUMD_STEP(0x114)
  SUMD_STEP(0x118) SUMD_STEP(0x142) SUMD_STEP(0x143)
#undef SUMD_STEP
  { unsigned long long x = __builtin_bit_cast(unsigned long long, A);
    int l = __builtin_amdgcn_readlane((int)(unsigned)x, 63);
    int h = __builtin_amdgcn_readlane((int)(x >> 32), 63);
    A = __builtin_bit_cast(double, ((unsigned long long)(unsigned)h << 32) | (unsigned)l); }
  { unsigned long long x = __builtin_bit_cast(unsigned long long, Bv);
    int l = __builtin_amdgcn_readlane((int)(unsigned)x, 63);
    int h = __builtin_amdgcn_readlane((int)(x >> 32), 63);
    Bv = __builtin_bit_cast(double, ((unsigned long long)(unsigned)h << 32) | (unsigned)l); }
  c = rl63(c); d = rl63(d);
}

// Phase-1 decision on wave-uniform (S, C): returns true when converged.
__device__ __forceinline__ bool decide_f32(float S, float C,
                                           float& lo, float& hi, float& tau) {
  float f = S - C * tau;
  if (f > 1.f) lo = tau; else hi = tau;
  float next;
  if (C > 0.5f) {
    float cand = (S - 1.f) / C;
    if (cand == tau) return true;
    next = (cand > lo && cand < hi) ? cand : 0.5f * (lo + hi);
  } else {
    next = 0.5f * (lo + hi);
  }
  if (next == tau) return true;
  tau = next;
  return false;
}
// Phase-2 decision (f64 exact segment root).
__device__ __forceinline__ bool decide_f64(double S, double C,
                                           double& lo, double& hi, double& tau) {
  double f = S - C * tau;
  if (f == 1.0 && C > 0.5) return true;
  if (f > 1.0) lo = tau; else hi = tau;
  double next;
  if (C > 0.5) {
    double cand = (S - 1.0) / C;
    if (cand == tau) return true;
    next = (cand > lo && cand < hi) ? cand : 0.5 * (lo + hi);
  } else {
    next = 0.5 * (lo + hi);
  }
  if (next == tau) return true;
  tau = next;
  return false;
}

__global__ __launch_bounds__(256)
void csparsemax_kernel(const float* __restrict__ z, const float* __restrict__ u,
                       float* __restrict__ out, int B) {
  constexpr int K = 1024;
  const int lane = threadIdx.x & 63;
  const int wv = threadIdx.x >> 6;
  const int row0 = (blockIdx.x * 4 + wv) * 2;
  if (row0 >= B) return;
  int row1 = row0 + 1;
  if (row1 >= B) row1 = row0;                 // duplicate work, identical writes
  const size_t base0 = (size_t)row0 * (size_t)K;
  const size_t base1 = (size_t)row1 * (size_t)K;

  // --- load both rows: 16 float4 loads issued together ---
  float zf0[16], uf0[16], zf1[16], uf1[16];
  {
    const vfloat4* zp0 = (const vfloat4*)(z + base0);
    const vfloat4* up0 = (const vfloat4*)(u + base0);
    const vfloat4* zp1 = (const vfloat4*)(z + base1);
    const vfloat4* up1 = (const vfloat4*)(u + base1);
    #pragma unroll
    for (int j = 0; j < 4; ++j) {
      vfloat4 a0 = zp0[j * 64 + lane];
      vfloat4 b0 = up0[j * 64 + lane];
      vfloat4 a1 = zp1[j * 64 + lane];
      vfloat4 b1 = up1[j * 64 + lane];
      zf0[j*4+0]=a0.x; zf0[j*4+1]=a0.y; zf0[j*4+2]=a0.z; zf0[j*4+3]=a0.w;
      uf0[j*4+0]=b0.x; uf0[j*4+1]=b0.y; uf0[j*4+2]=b0.z; uf0[j*4+3]=b0.w;
      zf1[j*4+0]=a1.x; zf1[j*4+1]=a1.y; zf1[j*4+2]=a1.z; zf1[j*4+3]=a1.w;
      uf1[j*4+0]=b1.x; uf1[j*4+1]=b1.y; uf1[j*4+2]=b1.z; uf1[j*4+3]=b1.w;
    }
  }

  // --- brackets + sum(u), both rows via interleaved DPP chains ---
  float a0 = -3.4028235e38f, m0 = -3.4028235e38f, s0 = 0.f;
  float a1 = -3.4028235e38f, m1 = -3.4028235e38f, s1 = 0.f;
  #pragma unroll
  for (int t = 0; t < 16; ++t) {
    a0 = fmaxf(a0, uf0[t] - zf0[t]);   // lo = -max(u-z)
    m0 = fmaxf(m0, zf0[t]);
    s0 += uf0[t];
    a1 = fmaxf(a1, uf1[t] - zf1[t]);
    m1 = fmaxf(m1, zf1[t]);
    s1 += uf1[t];
  }
  wave_max4(a0, m0, a1, m1);
  wave_sum2(s0, s1);
  float lo0 = -a0, hi0 = m0, lo1 = -a1, hi1 = m1;
  const double glo0 = (double)lo0, ghi0 = (double)hi0;
  const double glo1 = (double)lo1, ghi1 = (double)hi1;

  // --- phase 1: f32 segment-Newton, both rows interleaved ---
  float tau0 = (lo0 + hi0 * (s0 - 1.f)) / s0;
  if (!(tau0 > lo0 && tau0 < hi0)) tau0 = 0.5f * (lo0 + hi0);
  float tau1 = (lo1 + hi1 * (s1 - 1.f)) / s1;
  if (!(tau1 > lo1 && tau1 < hi1)) tau1 = 0.5f * (lo1 + hi1);
  bool d0 = false, d1 = false;
  for (int it = 0; it < 32; ++it) {
    float S0a=0.f,S0b=0.f,C0a=0.f,C0b=0.f;
    float S1a=0.f,S1b=0.f,C1a=0.f,C1b=0.f;
    #pragma unroll
    for (int t = 0; t < 16; t += 2) {
      float xa = zf0[t] - tau0,   xb = zf0[t+1] - tau0;
      float ya = zf1[t] - tau1,   yb = zf1[t+1] - tau1;
      S0a += (xa >= uf0[t])   ? uf0[t]   : ((xa > 0.f) ? zf0[t]   : 0.f);
      S0b += (xb >= uf0[t+1]) ? uf0[t+1] : ((xb > 0.f) ? zf0[t+1] : 0.f);
      S1a += (ya >= uf1[t])   ? uf1[t]   : ((ya > 0.f) ? zf1[t]   : 0.f);
      S1b += (yb >= uf1[t+1]) ? uf1[t+1] : ((yb > 0.f) ? zf1[t+1] : 0.f);
      C0a += (xa > 0.f && xa < uf0[t])   ? 1.f : 0.f;
      C0b += (xb > 0.f && xb < uf0[t+1]) ? 1.f : 0.f;
      C1a += (ya > 0.f && ya < uf1[t])   ? 1.f : 0.f;
      C1b += (yb > 0.f && yb < uf1[t+1]) ? 1.f : 0.f;
    }
    float S0 = S0a + S0b, C0 = C0a + C0b;
    float S1 = S1a + S1b, C1 = C1a + C1b;
    wave_sum4(S0, C0, S1, C1);
    if (!d0) d0 = decide_f32(S0, C0, lo0, hi0, tau0);
    if (!d1) d1 = decide_f32(S1, C1, lo1, hi1, tau1);
    if (d0 && d1) break;
  }

  // --- phase 2: f64 polish, both rows interleaved ---
  double dlo0 = glo0, dhi0 = ghi0, taud0 = (double)tau0;
  double dlo1 = glo1, dhi1 = ghi1, taud1 = (double)tau1;
  d0 = d1 = false;
  for (int it = 0; it < 24; ++it) {
    double Sd0 = 0.0, Sd1 = 0.0;
    float Cf0 = 0.f, Cf1 = 0.f;
    #pragma unroll
    for (int t = 0; t < 16; ++t) {
      double x = (double)zf0[t] - taud0;
      double ud = (double)uf0[t];
      if (x >= ud)      { Sd0 += ud; }
      else if (x > 0.0) { Sd0 += (double)zf0[t]; Cf0 += 1.f; }
      double y = (double)zf1[t] - taud1;
      double vd = (double)uf1[t];
      if (y >= vd)      { Sd1 += vd; }
      else if (y > 0.0) { Sd1 += (double)zf1[t]; Cf1 += 1.f; }
    }
    wave_sumd2_f2(Sd0, Sd1, Cf0, Cf1);
    if (!d0) d0 = decide_f64(Sd0, (double)Cf0, dlo0, dhi0, taud0);
    if (!d1) d1 = decide_f64(Sd1, (double)Cf1, dlo1, dhi1, taud1);
    if (d0 && d1) break;
  }

  // --- epilogue: p/val f32, regions via f64 compares, NT stores ---
  float* out_p = out;
  float* out_r = out + (size_t)B * (size_t)K;
  float* out_t = out + 2ull * (size_t)B * (size_t)K;
  float* out_v = out_t + B;

  const float tf0 = (float)taud0, tf1 = (float)taud1;
  float v0 = 0.f, v1 = 0.f;
  #pragma unroll
  for (int j = 0; j < 4; ++j) {
    vfloat4 p4, r4, q4, w4;
    #pragma unroll
    for (int q = 0; q < 4; ++q) {
      int t = j * 4 + q;
      float pf = fminf(fmaxf(zf0[t] - tf0, 0.f), uf0[t]);
      float df = pf - zf0[t];
      v0 = fmaf(df, df, v0);
      double xd = (double)zf0[t] - taud0;
      p4[q] = pf;
      r4[q] = (xd <= 0.0) ? 0.f : ((xd >= (double)uf0[t]) ? 2.f : 1.f);
      float pg = fminf(fmaxf(zf1[t] - tf1, 0.f), uf1[t]);
      float dg = pg - zf1[t];
      v1 = fmaf(dg, dg, v1);
      double yd = (double)zf1[t] - taud1;
      q4[q] = pg;
      w4[q] = (yd <= 0.0) ? 0.f : ((yd >= (double)uf1[t]) ? 2.f : 1.f);
    }
    __builtin_nontemporal_store(p4, &((vfloat4*)(out_p + base0))[j * 64 + lane]);
    __builtin_nontemporal_store(r4, &((vfloat4*)(out_r + base0))[j * 64 + lane]);
    __builtin_nontemporal_store(q4, &((vfloat4*)(out_p + base1))[j * 64 + lane]);
    __builtin_nontemporal_store(w4, &((vfloat4*)(out_r + base1))[j * 64 + lane]);
  }

  wave_sum2(v0, v1);
  if (lane == 0) {
    out_t[row0] = tf0;
    out_v[row0] = 0.5f * v0;
    out_t[row1] = tf1;
    out_v[row1] = 0.5f * v1;
  }
}

extern "C" void kernel_launch(void* const* d_in, const int* in_sizes, int n_in,
                              void* d_out, int out_size, void* d_ws, size_t ws_size,
                              hipStream_t stream) {
  const float* z = (const float*)d_in[0];
  const float* u = (const float*)d_in[1];
  float* out = (float*)d_out;
  const int K = 1024;
  const int B = in_sizes[0] / K;
  const int rows_per_block = 8;               // 4 waves x 2 rows
  const int blocks = (B + rows_per_block - 1) / rows_per_block;
  csparsemax_kernel<<<blocks, 256, 0, stream>>>(z, u, out, B);
}

// Round 9
// 38.317 us; speedup vs baseline: 1.7467x; 1.7467x over previous
//
#include <hip/hip_runtime.h>

// Constrained sparsemax: p = clip(z - tau, 0, u), tau s.t. sum p = 1.
// R7 core: one wave per row, DPP reductions, NT stores, f64 polish on the
// GLOBAL bracket (required: regions must match numpy's f64 tau to ~1e-15).
// New in R9: phase 1 is SECANT on f(tau) = sum med3(z-tau,0,u) - cheapest
// possible iteration (3 VALU ops/elem, ONE DPP chain) with bracket clip +
// midpoint fallback. Secant through two points in the same linear segment
// lands exactly (same finite convergence as segment-Newton).

typedef float vfloat4 __attribute__((ext_vector_type(4)));

template<int CTRL>
__device__ __forceinline__ float dpp_zero(float v) {   // invalid lanes -> 0
  return __builtin_bit_cast(float,
    __builtin_amdgcn_update_dpp(0, __builtin_bit_cast(int, v), CTRL, 0xf, 0xf, true));
}
template<int CTRL>
__device__ __forceinline__ float dpp_ident(float v, float ident) { // invalid -> ident
  return __builtin_bit_cast(float,
    __builtin_amdgcn_update_dpp(__builtin_bit_cast(int, ident),
                                __builtin_bit_cast(int, v), CTRL, 0xf, 0xf, false));
}
__device__ __forceinline__ float rl63(float v) {
  return __builtin_bit_cast(float,
    __builtin_amdgcn_readlane(__builtin_bit_cast(int, v), 63));
}

__device__ __forceinline__ float wave_sum(float v) {
  v += dpp_zero<0x111>(v); v += dpp_zero<0x112>(v); v += dpp_zero<0x114>(v);
  v += dpp_zero<0x118>(v); v += dpp_zero<0x142>(v); v += dpp_zero<0x143>(v);
  return rl63(v);
}
// init: two maxes + one sum, chains interleaved per level
__device__ __forceinline__ void wave_mms(float& a, float& b, float& s) {
  const float NI = -3.4028235e38f;
#define MMS_STEP(CT) \
  a = fmaxf(a, dpp_ident<CT>(a, NI)); b = fmaxf(b, dpp_ident<CT>(b, NI)); \
  s += dpp_zero<CT>(s);
  MMS_STEP(0x111) MMS_STEP(0x112) MMS_STEP(0x114)
  MMS_STEP(0x118) MMS_STEP(0x142) MMS_STEP(0x143)
#undef MMS_STEP
  a = rl63(a); b = rl63(b); s = rl63(s);
}
// phase 2: one f64 sum + one f32 sum, interleaved
__device__ __forceinline__ void wave_sumd_f(double& A, float& c) {
#define SUMD_STEP(CT) { \
  unsigned long long xa = __builtin_bit_cast(unsigned long long, A); \
  int al = __builtin_amdgcn_update_dpp(0, (int)(unsigned)xa, CT, 0xf, 0xf, true); \
  int ah = __builtin_amdgcn_update_dpp(0, (int)(xa >> 32),   CT, 0xf, 0xf, true); \
  c += dpp_zero<CT>(c); \
  A += __builtin_bit_cast(double, ((unsigned long long)(unsigned)ah << 32) | (unsigned)al); }
  SUMD_STEP(0x111) SUMD_STEP(0x112) SUMD_STEP(0x114)
  SUMD_STEP(0x118) SUMD_STEP(0x142) SUMD_STEP(0x143)
#undef SUMD_STEP
  { unsigned long long x = __builtin_bit_cast(unsigned long long, A);
    int l = __builtin_amdgcn_readlane((int)(unsigned)x, 63);
    int h = __builtin_amdgcn_readlane((int)(x >> 32), 63);
    A = __builtin_bit_cast(double, ((unsigned long long)(unsigned)h << 32) | (unsigned)l); }
  c = rl63(c);
}

__global__ __launch_bounds__(256)
void csparsemax_kernel(const float* __restrict__ z, const float* __restrict__ u,
                       float* __restrict__ out, int B) {
  constexpr int K = 1024;
  const int lane = threadIdx.x & 63;
  const int wv = threadIdx.x >> 6;
  const int row = blockIdx.x * 4 + wv;
  if (row >= B) return;
  const size_t base = (size_t)row * (size_t)K;

  // --- load 16 elems/lane as 4x float4, coalesced ---
  float zf[16], uf[16];
  const vfloat4* z4p = (const vfloat4*)(z + base);
  const vfloat4* u4p = (const vfloat4*)(u + base);
  #pragma unroll
  for (int j = 0; j < 4; ++j) {
    vfloat4 a = z4p[j * 64 + lane];
    vfloat4 b = u4p[j * 64 + lane];
    zf[j*4+0] = a.x; zf[j*4+1] = a.y; zf[j*4+2] = a.z; zf[j*4+3] = a.w;
    uf[j*4+0] = b.x; uf[j*4+1] = b.y; uf[j*4+2] = b.z; uf[j*4+3] = b.w;
  }

  // --- bracket [lo,hi] + sum(u): f(lo)=sum u >= 1 > 0 = f(hi) ---
  float a = -3.4028235e38f, m = -3.4028235e38f, su = 0.f;
  #pragma unroll
  for (int t = 0; t < 16; ++t) {
    a = fmaxf(a, uf[t] - zf[t]);    // lo = -max(u-z) = min(z-u)
    m = fmaxf(m, zf[t]);
    su += uf[t];
  }
  wave_mms(a, m, su);
  float lo = -a, hi = m;
  const double glo = (double)lo, ghi = (double)hi;

  // --- phase 1: secant on g(tau) = sum med3(z-tau,0,u) - 1 ---
  float t_prev = hi, g_prev = -1.f;              // g(hi) = -1
  float tau = (lo + hi * (su - 1.f)) / su;       // secant((lo,su-1),(hi,-1))
  if (!(tau > lo && tau < hi)) tau = 0.5f * (lo + hi);
  for (int it = 0; it < 48; ++it) {
    float f0 = 0.f, f1 = 0.f, f2 = 0.f, f3 = 0.f;
    #pragma unroll
    for (int t = 0; t < 16; t += 4) {            // v_med3_f32 per elem
      f0 += fminf(fmaxf(zf[t+0] - tau, 0.f), uf[t+0]);
      f1 += fminf(fmaxf(zf[t+1] - tau, 0.f), uf[t+1]);
      f2 += fminf(fmaxf(zf[t+2] - tau, 0.f), uf[t+2]);
      f3 += fminf(fmaxf(zf[t+3] - tau, 0.f), uf[t+3]);
    }
    float g = wave_sum((f0 + f1) + (f2 + f3)) - 1.f;
    if (g == 0.f) break;
    if (g > 0.f) lo = tau; else hi = tau;
    // secant root through (t_prev, g_prev), (tau, g); NaN/inf/out-of-bracket
    // all fail the range check -> midpoint fallback
    float cand = (tau * g_prev - t_prev * g) / (g_prev - g);
    t_prev = tau; g_prev = g;
    float next = (cand > lo && cand < hi) ? cand : 0.5f * (lo + hi);
    if (next == tau) break;                      // f32 resolution reached
    tau = next;
  }

  // --- phase 2: f64 segment-Newton polish, GLOBAL bracket (exactness) ---
  double dlo = glo, dhi = ghi, taud = (double)tau;
  for (int it = 0; it < 24; ++it) {
    double Sd = 0.0;
    float Cf = 0.f;                              // count exact in f32
    #pragma unroll
    for (int t = 0; t < 16; ++t) {
      double x = (double)zf[t] - taud;
      double ud = (double)uf[t];
      if (x >= ud)      { Sd += ud; }
      else if (x > 0.0) { Sd += (double)zf[t]; Cf += 1.f; }
    }
    wave_sumd_f(Sd, Cf);
    double C = (double)Cf;
    double f = Sd - C * taud;
    if (f == 1.0 && C > 0.5) break;
    if (f > 1.0) dlo = taud; else dhi = taud;
    double next;
    if (C > 0.5) {
      double cand = (Sd - 1.0) / C;              // exact segment root
      if (cand == taud) break;
      next = (cand > dlo && cand < dhi) ? cand : 0.5 * (dlo + dhi);
    } else {
      next = 0.5 * (dlo + dhi);
    }
    if (next == taud) break;
    taud = next;
  }

  // --- epilogue: p/val in f32, regions via f64 compares, NT stores ---
  float* out_p = out;
  float* out_r = out + (size_t)B * (size_t)K;
  float* out_t = out + 2ull * (size_t)B * (size_t)K;
  float* out_v = out_t + B;

  const float tf = (float)taud;
  float vloc = 0.f;
  #pragma unroll
  for (int j = 0; j < 4; ++j) {
    vfloat4 p4, r4;
    #pragma unroll
    for (int q = 0; q < 4; ++q) {
      int t = j * 4 + q;
      float pf = fminf(fmaxf(zf[t] - tf, 0.f), uf[t]);   // v_med3_f32
      float d = pf - zf[t];
      vloc = fmaf(d, d, vloc);
      double xd = (double)zf[t] - taud;                  // numpy-exact bounds
      float rg = (xd <= 0.0) ? 0.f : ((xd >= (double)uf[t]) ? 2.f : 1.f);
      p4[q] = pf;
      r4[q] = rg;
    }
    __builtin_nontemporal_store(p4, &((vfloat4*)(out_p + base))[j * 64 + lane]);
    __builtin_nontemporal_store(r4, &((vfloat4*)(out_r + base))[j * 64 + lane]);
  }

  float vtot = wave_sum(vloc);
  if (lane == 0) {
    out_t[row] = tf;
    out_v[row] = 0.5f * vtot;
  }
}

extern "C" void kernel_launch(void* const* d_in, const int* in_sizes, int n_in,
                              void* d_out, int out_size, void* d_ws, size_t ws_size,
                              hipStream_t stream) {
  const float* z = (const float*)d_in[0];
  const float* u = (const float*)d_in[1];
  float* out = (float*)d_out;
  const int K = 1024;
  const int B = in_sizes[0] / K;
  const int blocks = (B + 3) / 4;
  csparsemax_kernel<<<blocks, 256, 0, stream>>>(z, u, out, B);
}